// Round 13
// baseline (64.605 us; speedup 1.0000x reference)
//
#include <hip/hip_runtime.h>
#include <stdint.h>

// R13 = R12 + MLP batching in main: all 20 A-frag loads (4 b x 5 s) issued before
// any MFMA -> 4 exposed L2/L3 latency windows collapse to 1. R12 post-mortem:
// 4x b-blocking moved only 0.3 µs => main is latency-bound, not issue-bound.
//   C[b*G+g, f] = sum_k A[g,k]*W[k,f], k=ij*16+d (144 real, padded to 160).
// A frag (l15,quad,s): k=s*32+quad*8+{0..7} -> ij=2s+(quad>>1), d0=(quad&1)*8.

#define NOBJ 32
#define NG   4960
#define NF   16
#define ND   16
#define KP   160
#define SLICE (NOBJ * NOBJ * ND)        // 16384
#define RELEMS (32 * SLICE)             // 524288

typedef __bf16 bf16x8 __attribute__((ext_vector_type(8)));
typedef float  f32x4  __attribute__((ext_vector_type(4)));

__device__ __forceinline__ unsigned f2bf1(float x) {
    unsigned u = __float_as_uint(x);
    return (u + 0x7fffu + ((u >> 16) & 1u)) >> 16;   // RNE; inputs finite
}
__device__ __forceinline__ unsigned packbf(float lo, float hi) {
    return f2bf1(lo) | (f2bf1(hi) << 16);
}

__device__ __forceinline__ int C3i(int x) { return (x * (x - 1) * (x - 2)) / 6; } // x<=34
__device__ __forceinline__ int C2i(int x) { return (x * (x - 1)) >> 1; }

// Combinatorial-number-system inversion, branchless fixups (R8-verified bit-exact).
__device__ __forceinline__ void unrank3_cf(int g, int& t0, int& t1, int& t2) {
    const int T = 4960 - g;                                  // [1,4960]
    int x = (int)cbrtf(6.0f * (float)T) + 1;
    x += (C3i(x) < T);
    x += (C3i(x) < T);
    x -= (C3i(x - 1) >= T);
    x -= (C3i(x - 1) >= T);
    t0 = 32 - x;
    const int rem2 = C3i(x) - T;
    const int T2   = C2i(x - 1) - rem2;
    int y = (int)(sqrtf(2.0f * (float)T2) + 0.5f);
    y += (C2i(y) < T2);
    y += (C2i(y) < T2);
    y -= (C2i(y - 1) >= T2);
    y -= (C2i(y - 1) >= T2);
    t1 = 32 - y;
    t2 = t1 + 1 + (C2i(y) - T2);
}

// grid 257 blocks: 0..255 convert R (8 elems/thread), block 256 builds padded W^T.
__global__ __launch_bounds__(256) void rgc_pre(
    const float* __restrict__ R, const float* __restrict__ Fw,
    unsigned short* __restrict__ Rbf, unsigned short* __restrict__ Wpad)
{
    const int tid = threadIdx.x;
    if (blockIdx.x < 256) {
        const int e = (blockIdx.x * 256 + tid) * 8;
        const float4* p = (const float4*)(R + e);
        const float4 v0 = p[0], v1 = p[1];
        uint4 o;
        o.x = packbf(v0.x, v0.y); o.y = packbf(v0.z, v0.w);
        o.z = packbf(v1.x, v1.y); o.w = packbf(v1.z, v1.w);
        *(uint4*)(Rbf + e) = o;
    } else {
        for (int e = tid * 8; e < NF * KP; e += 256 * 8) {   // 320 slots / 256 thr
            const int f = e / KP, k0 = e % KP;
            uint4 o = make_uint4(0u, 0u, 0u, 0u);
            if (k0 < 144) {
                const float4* p = (const float4*)(Fw + f * 144 + k0);
                const float4 v0 = p[0], v1 = p[1];
                o.x = packbf(v0.x, v0.y); o.y = packbf(v0.z, v0.w);
                o.z = packbf(v1.x, v1.y); o.w = packbf(v1.z, v1.w);
            }
            *(uint4*)(Wpad + e) = o;                         // Wpad[f][k], k>=144 zeroed
        }
    }
}

__global__ __launch_bounds__(256) void rgc_main(
    const unsigned short* __restrict__ Rbf,   // bf16 bits, (32,32,32,16)
    const unsigned short* __restrict__ Wpad,  // bf16 bits, (16,160) zero-padded
    float* __restrict__ out)                  // (32,4960,16)
{
    const int tid  = threadIdx.x;
    const int wave = tid >> 6;
    const int lane = tid & 63;
    const int l15  = lane & 15;               // A row (group) / B row (=f) / C col (=f)
    const int quad = lane >> 4;               // k-subchunk / C row-group
    const int b0   = blockIdx.y * 4;          // 4 batches per block
    const int gw   = blockIdx.x * 64 + wave * 16;

    const int g = min(gw + l15, NG - 1);      // clamp; stores masked below
    int t0, t1, t2;
    unrank3_cf(g, t0, t1, t2);
    const int t[3] = {t0, t1, t2};

    int rowoff[9];
#pragma unroll
    for (int ij = 0; ij < 9; ++ij) {
        const int i = ij / 3, j = ij % 3;     // compile-time
        rowoff[ij] = (t[i] * NOBJ + t[j]) * ND;
    }

    const int hi = quad >> 1;
    const int d0 = (quad & 1) * 8;
    int ro[5];
    ro[0] = hi ? rowoff[1] : rowoff[0];
    ro[1] = hi ? rowoff[3] : rowoff[2];
    ro[2] = hi ? rowoff[5] : rowoff[4];
    ro[3] = hi ? rowoff[7] : rowoff[6];
    ro[4] = rowoff[8];                        // s=4,hi=1 -> k>=144: W pad is 0

    // ---- issue ALL loads first: 5 W-frags + 20 A-frags, independent (MLP=25) ----
    const unsigned short* wbase = Wpad + l15 * KP + quad * 8;
    bf16x8 wf[5];
#pragma unroll
    for (int s = 0; s < 5; ++s) wf[s] = *(const bf16x8*)(wbase + s * 32);

    bf16x8 af[4][5];
#pragma unroll
    for (int bb = 0; bb < 4; ++bb) {
        const unsigned short* Rb = Rbf + (size_t)(b0 + bb) * SLICE;
#pragma unroll
        for (int s = 0; s < 5; ++s)
            af[bb][s] = *(const bf16x8*)(Rb + ro[s] + d0);
    }

    // ---- then all MFMAs (per-acc s-order unchanged -> numerics identical) ----
    f32x4 acc[4];
#pragma unroll
    for (int bb = 0; bb < 4; ++bb) acc[bb] = (f32x4){0.f, 0.f, 0.f, 0.f};
#pragma unroll
    for (int s = 0; s < 5; ++s)
#pragma unroll
        for (int bb = 0; bb < 4; ++bb)
            acc[bb] = __builtin_amdgcn_mfma_f32_16x16x32_bf16(af[bb][s], wf[s], acc[bb], 0, 0, 0);

    // ---- stores: C[row=quad*4+r][col=l15] -> out[b][gbase+r][f=l15] ----
    const int gbase = gw + quad * 4;
#pragma unroll
    for (int bb = 0; bb < 4; ++bb) {
        const size_t obase = ((size_t)(b0 + bb) * NG + gbase) * NF + l15;
#pragma unroll
        for (int r = 0; r < 4; ++r) {
            const int gg = gbase + r;
            if (gg < NG) out[obase + (size_t)r * NF] = acc[bb][r];
        }
    }
}

extern "C" void kernel_launch(void* const* d_in, const int* in_sizes, int n_in,
                              void* d_out, int out_size, void* d_ws, size_t ws_size,
                              hipStream_t stream) {
    const float* R  = (const float*)d_in[0];
    const float* Fw = (const float*)d_in[1];
    if (n_in >= 2 && in_sizes[0] == NF * 9 * ND) { R = (const float*)d_in[1]; Fw = (const float*)d_in[0]; }
    float* out = (float*)d_out;

    unsigned short* Rbf  = (unsigned short*)d_ws;                       // 1 MB
    unsigned short* Wpad = (unsigned short*)((char*)d_ws + RELEMS * 2); // 5 KB

    rgc_pre<<<dim3(257, 1), dim3(256, 1, 1), 0, stream>>>(R, Fw, Rbf, Wpad);
    dim3 grid((NG + 63) / 64, 8);    // 78 x 8 blocks, 4 batches per block
    rgc_main<<<grid, dim3(256, 1, 1), 0, stream>>>(Rbf, Wpad, out);
}